// Round 6
// baseline (224.558 us; speedup 1.0000x reference)
//
#include <hip/hip_runtime.h>
#include <math.h>

#define T_LEN 100
#define K_LEN 25
#define DLAT 64
#define DHID 128
#define CST 68    // h2s/aggs row stride (floats)
#define AST2 36   // packed adjacency row stride (u32; 32 data + 4 pad, 16B-aligned rows)

__device__ __forceinline__ float dot4(float4 a, float4 b) {
    return a.x * b.x + a.y * b.y + a.z * b.z + a.w * b.w;
}

// ---------------------------------------------------------------------------
// packU (one tiny dispatch):
//  - Wp[(t4*64+c)*4+r] = W[c][t4*4+r]  (collapsed Conv1d+fc1, packed so the
//    encoder's per-lane (lane=channel) float4 load is coalesced: 64 lanes
//    read one contiguous 1KB line per t4)
//  - Wp[6400+c] = b2[c]
//  - upk[((mc*128)+j)*8+k]: interleaved rel/root rows, [mc][j][8] layout so
//    part-4 weight reads are lane-coalesced
//  - bar[0] = 0 (done-counter for the last-block D/E tail)
// ---------------------------------------------------------------------------
__global__ __launch_bounds__(256) void packU(const float* __restrict__ conv_w,
                                             const float* __restrict__ conv_b,
                                             const float* __restrict__ fc1_w,
                                             const float* __restrict__ fc1_b,
                                             const float* __restrict__ rel_w,
                                             const float* __restrict__ root_w,
                                             float* __restrict__ Wp,
                                             float* __restrict__ upk,
                                             unsigned* __restrict__ bar) {
    int idx = blockIdx.x * 256 + threadIdx.x;
    if (idx < 16384) {
        int mc = idx >> 10, rem = idx & 1023;
        int j = rem >> 3, k = rem & 7;
        upk[idx] = (mc < 8) ? rel_w[j * DLAT + mc * 8 + k]
                            : root_w[j * DLAT + (mc - 8) * 8 + k];
    } else if (idx < 16384 + 6400) {
        int t2 = idx - 16384;
        int c = t2 / T_LEN, i = t2 % T_LEN;
        int t0 = i - 12 > 0 ? i - 12 : 0;
        int t1 = i + 12 < T_LEN - 1 ? i + 12 : T_LEN - 1;
        float acc = 0.f;
        for (int t = t0; t <= t1; ++t)
            acc += fc1_w[t] * conv_w[c * K_LEN + (i - t + 12)];
        Wp[((i >> 2) * 64 + c) * 4 + (i & 3)] = acc;
    } else if (idx < 16384 + 6400 + 64) {
        int c = idx - (16384 + 6400);
        float S = 0.f;
        for (int t = 0; t < T_LEN; ++t) S += fc1_w[t];
        Wp[6400 + c] = conv_b[c] * S + fc1_b[0];
    } else if (idx == 16384 + 6400 + 64) {
        bar[0] = 0u;
    }
}

// ---------------------------------------------------------------------------
// fused: one block per graph, 512 thr = 8 waves. LDS 46.6KB -> 3 blocks/CU
// (24 waves/CU — the r5 lesson: this kernel is latency-bound; concurrency,
// not instruction count, sets the duration).
// zone (26.6KB) time-shares: x-stage -> [adj(9KB) | aggs(17.4KB)] -> Sred/Qred
//   0 issue 2048 strided edge loads -> regs; stage x -> LDS           S1
//   1 encoder: lane=channel, Wp per-lane coalesced global, x bcast    S2
//   2 zero packed adj                                                 S3
//     LDS-atomic edge count (2 u16 counts per u32)                    S4
//   3 agg = A @ h2 (unpack counts inline)                             S5
//   4 part4: lane owns j=lane & lane+64; wave owns 8 nodes; weights
//     software-pipelined (double-buffered regs) from coalesced upk    S6
//   5 reduce -> Sg/Qg; last-done block runs BN-stats + head (D+E)
// ---------------------------------------------------------------------------
__global__ __launch_bounds__(512, 6) void fused(const float* __restrict__ x,
                                                const int* __restrict__ ei,
                                                const float* __restrict__ Wp,
                                                const float* __restrict__ upk,
                                                const float* __restrict__ rel_b,
                                                const float* __restrict__ gamma,
                                                const float* __restrict__ beta,
                                                const float* __restrict__ fc2_w,
                                                const float* __restrict__ fc2_b,
                                                float* __restrict__ Sg,
                                                float* __restrict__ Qg,
                                                float* __restrict__ y,
                                                unsigned* __restrict__ bar,
                                                int E, int G, int N) {
    __shared__ float h2s[64 * CST];     // 17408 B
    __shared__ float zone[6656];        // 26624 B: x | (adj + aggs) | Sred/Qred
    __shared__ float fw_s[3 * DHID];
    __shared__ float ab_s[2 * DHID];
    __shared__ int flag_s;

    float* xz = zone;                       // 6400 f32 (x stage)
    unsigned* Asu = (unsigned*)zone;        // 64*36 u32 packed counts
    float* aggs = zone + 2304;              // 64*68 f32
    float* Sred = zone;                     // 1024 f32 (post-part4)
    float* Qred = zone + 1024;              // 1024 f32

    const int tid = threadIdx.x;
    const int lane = tid & 63;
    const int w2 = __builtin_amdgcn_readfirstlane(tid >> 6);  // 0..7

    // bijective XCD swizzle (m204)
    const int nb = gridDim.x;
    int qq = nb >> 3, rr = nb & 7;
    int xc = blockIdx.x & 7, oo = blockIdx.x >> 3;
    const int g = (xc < rr ? xc * (qq + 1) : rr * (qq + 1) + (xc - rr) * qq) + oo;

    const int epg = (G > 0) ? E / G : 0;
    const bool fast = (epg == 2048) && (E == G * 2048);

    // ---- 0. issue strided edge loads EARLY (drain after encoder) ----
    int es0 = 0, es1 = 0, es2 = 0, es3 = 0;
    int ed0 = 0, ed1 = 0, ed2 = 0, ed3 = 0;
    if (fast) {
        int e0 = g + tid * G;
        int st = 512 * G;
        es0 = ei[e0];           ed0 = ei[E + e0];
        es1 = ei[e0 + st];      ed1 = ei[E + e0 + st];
        es2 = ei[e0 + 2 * st];  ed2 = ei[E + e0 + 2 * st];
        es3 = ei[e0 + 3 * st];  ed3 = ei[E + e0 + 3 * st];
    }

    // stage x rows (coalesced float4)
    {
        const float4* xg4 = (const float4*)(x + (size_t)g * 64 * T_LEN);
        for (int i = tid; i < 1600; i += 512) ((float4*)xz)[i] = xg4[i];
    }
    __syncthreads();  // S1

    // ---- 1. encoder: lane = channel c; wave w2 owns nodes [8w2, 8w2+8) ----
    {
        const float4* Wp4 = (const float4*)Wp;  // [t4][c] coalesced
        float acc[8];
#pragma unroll
        for (int k = 0; k < 8; ++k) acc[k] = 0.f;
#pragma unroll
        for (int t4 = 0; t4 < 25; ++t4) {
            float4 wv = Wp4[t4 * 64 + lane];    // per-lane, 1KB/wave coalesced
#pragma unroll
            for (int k = 0; k < 8; ++k) {
                float4 xv = *(const float4*)&xz[(w2 * 8 + k) * T_LEN + t4 * 4];  // bcast
                acc[k] += dot4(wv, xv);
            }
        }
        float bb = Wp[6400 + lane];
#pragma unroll
        for (int k = 0; k < 8; ++k)
            h2s[(w2 * 8 + k) * CST + lane] = acc[k] + bb;
    }
    __syncthreads();  // S2 (x dead)

    // ---- 2. zero packed adjacency, then LDS-atomic edge count ----
    for (int i = tid; i < 64 * AST2; i += 512) Asu[i] = 0u;
    __syncthreads();  // S3
    if (fast) {
        atomicAdd(&Asu[(ed0 & 63) * AST2 + ((es0 & 63) >> 1)], 1u << ((es0 & 1) << 4));
        atomicAdd(&Asu[(ed1 & 63) * AST2 + ((es1 & 63) >> 1)], 1u << ((es1 & 1) << 4));
        atomicAdd(&Asu[(ed2 & 63) * AST2 + ((es2 & 63) >> 1)], 1u << ((es2 & 1) << 4));
        atomicAdd(&Asu[(ed3 & 63) * AST2 + ((es3 & 63) >> 1)], 1u << ((es3 & 1) << 4));
    } else {
        for (int e = g + tid * G; e < E; e += 512 * G) {
            int s = ei[e] & 63, d = ei[E + e] & 63;
            atomicAdd(&Asu[d * AST2 + (s >> 1)], 1u << ((s & 1) << 4));
        }
    }
    __syncthreads();  // S4

    // ---- 3. agg = A @ h2 (unpack 2 counts per u32 inline) ----
    {
        int c4 = (tid & 15) * 4;
        int n0 = tid >> 4;  // 0..31
#pragma unroll
        for (int i = 0; i < 2; ++i) {
            int n = n0 + 32 * i;
            float4 a4 = {0.f, 0.f, 0.f, 0.f};
#pragma unroll 2
            for (int s8 = 0; s8 < 8; ++s8) {
                uint4 au = *(const uint4*)&Asu[n * AST2 + s8 * 4];  // srcs 8s8..+8
                float c0 = (float)(au.x & 0xffffu), c1 = (float)(au.x >> 16);
                float c2 = (float)(au.y & 0xffffu), c3 = (float)(au.y >> 16);
                float c4v = (float)(au.z & 0xffffu), c5 = (float)(au.z >> 16);
                float c6 = (float)(au.w & 0xffffu), c7 = (float)(au.w >> 16);
                const float* hb = &h2s[(8 * s8) * CST + c4];
                float4 h0 = *(const float4*)(hb + 0 * CST);
                float4 h1 = *(const float4*)(hb + 1 * CST);
                float4 h2v = *(const float4*)(hb + 2 * CST);
                float4 h3 = *(const float4*)(hb + 3 * CST);
                float4 h4 = *(const float4*)(hb + 4 * CST);
                float4 h5 = *(const float4*)(hb + 5 * CST);
                float4 h6 = *(const float4*)(hb + 6 * CST);
                float4 h7 = *(const float4*)(hb + 7 * CST);
                a4.x += c0 * h0.x + c1 * h1.x + c2 * h2v.x + c3 * h3.x +
                        c4v * h4.x + c5 * h5.x + c6 * h6.x + c7 * h7.x;
                a4.y += c0 * h0.y + c1 * h1.y + c2 * h2v.y + c3 * h3.y +
                        c4v * h4.y + c5 * h5.y + c6 * h6.y + c7 * h7.y;
                a4.z += c0 * h0.z + c1 * h1.z + c2 * h2v.z + c3 * h3.z +
                        c4v * h4.z + c5 * h5.z + c6 * h6.z + c7 * h7.z;
                a4.w += c0 * h0.w + c1 * h1.w + c2 * h2v.w + c3 * h3.w +
                        c4v * h4.w + c5 * h5.w + c6 * h6.w + c7 * h7.w;
            }
            *(float4*)&aggs[n * CST + c4] = a4;
        }
    }
    __syncthreads();  // S5

    // ---- 4. part4: lane owns j0=lane, j1=lane+64; wave owns 8 nodes.
    //      Weights double-buffered in registers (prefetch mc+1 under mc). ----
    {
        const float4* up4 = (const float4*)upk;
        float accJ[16];
#pragma unroll
        for (int k = 0; k < 16; ++k) accJ[k] = 0.f;

        int ia = lane * 2, ib = (lane + 64) * 2;
        float4 wa0 = up4[ia], wa1 = up4[ia + 1];
        float4 wb0 = up4[ib], wb1 = up4[ib + 1];

#pragma unroll
        for (int mc = 0; mc < 16; ++mc) {
            float4 na0, na1, nb0, nb1;
            if (mc < 15) {
                int ja = ((mc + 1) * 128 + lane) * 2;
                int jb = ((mc + 1) * 128 + lane + 64) * 2;
                na0 = up4[ja]; na1 = up4[ja + 1];
                nb0 = up4[jb]; nb1 = up4[jb + 1];
            }
            const float* zbase = (mc < 8) ? (aggs + mc * 8) : (h2s + (mc - 8) * 8);
#pragma unroll
            for (int nn = 0; nn < 8; ++nn) {
                const float* zr = zbase + (w2 * 8 + nn) * CST;   // bcast
                float4 z0 = *(const float4*)zr;
                float4 z1 = *(const float4*)(zr + 4);
                accJ[2 * nn] += dot4(wa0, z0) + dot4(wa1, z1);
                accJ[2 * nn + 1] += dot4(wb0, z0) + dot4(wb1, z1);
            }
            if (mc < 15) { wa0 = na0; wa1 = na1; wb0 = nb0; wb1 = nb1; }
        }

        float rb0 = rel_b[lane], rb1 = rel_b[lane + 64];
        float s0 = 0.f, q0 = 0.f, s1 = 0.f, q1 = 0.f;
#pragma unroll
        for (int nn = 0; nn < 8; ++nn) {
            float o0 = accJ[2 * nn] + rb0;
            s0 += o0; q0 += o0 * o0;
            float o1 = accJ[2 * nn + 1] + rb1;
            s1 += o1; q1 += o1 * o1;
        }
        __syncthreads();  // S6: aggs/adj reads done; zone becomes Sred/Qred
        Sred[w2 * DHID + lane] = s0;       Qred[w2 * DHID + lane] = q0;
        Sred[w2 * DHID + 64 + lane] = s1;  Qred[w2 * DHID + 64 + lane] = q1;
    }
    __syncthreads();  // S7

    if (tid < DHID) {
        float S = 0.f, Q = 0.f;
#pragma unroll
        for (int k = 0; k < 8; ++k) {
            S += Sred[k * DHID + tid];
            Q += Qred[k * DHID + tid];
        }
        Sg[(size_t)g * DHID + tid] = S;
        Qg[(size_t)g * DHID + tid] = Q;
    }
    __syncthreads();  // S8: Sg/Qg stores issued before fence

    if (tid == 0) {
        __threadfence();  // release this block's Sg/Qg
        unsigned old = __hip_atomic_fetch_add(&bar[0], 1u, __ATOMIC_ACQ_REL,
                                              __HIP_MEMORY_SCOPE_AGENT);
        flag_s = (old == (unsigned)nb - 1u) ? 1 : 0;
        if (flag_s) __threadfence();  // acquire all other blocks' writes
    }
    __syncthreads();
    if (!flag_s) return;

    // =============== last block only: D (BN stats) + E (head) ===============
    {
        int gq = tid >> 7, j = tid & 127;
        float s = 0.f, qv = 0.f;
        for (int gi = gq; gi < G; gi += 4) {
            s += Sg[(size_t)gi * DHID + j];
            qv += Qg[(size_t)gi * DHID + j];
        }
        Sred[gq * DHID + j] = s;
        Qred[gq * DHID + j] = qv;
    }
    for (int i = tid; i < 3 * DHID; i += 512) fw_s[i] = fc2_w[i];
    __syncthreads();
    if (tid < DHID) {
        float S = Sred[tid] + Sred[DHID + tid] + Sred[2 * DHID + tid] +
                  Sred[3 * DHID + tid];
        float Q = Qred[tid] + Qred[DHID + tid] + Qred[2 * DHID + tid] +
                  Qred[3 * DHID + tid];
        float inv_n = 1.f / (float)N;
        float mean = S * inv_n;
        float var = Q * inv_n - mean * mean;
        float a = rsqrtf(var + 1e-5f) * gamma[tid];
        float b = beta[tid] - mean * a;
        ab_s[tid] = a;
        ab_s[DHID + tid] = b;
    }
    __syncthreads();

    // E: one wave per graph; lane covers j=lane and j=lane+64
    {
        float fb0 = fc2_b[0], fb1 = fc2_b[1], fb2 = fc2_b[2];
        for (int gg = w2; gg < G; gg += 8) {
            float S0 = Sg[(size_t)gg * DHID + lane];
            float Q0 = Qg[(size_t)gg * DHID + lane];
            float S1 = Sg[(size_t)gg * DHID + 64 + lane];
            float Q1 = Qg[(size_t)gg * DHID + 64 + lane];
            float a0 = ab_s[lane], b0 = ab_s[DHID + lane];
            float a1 = ab_s[64 + lane], b1 = ab_s[DHID + 64 + lane];
            float p0 = (a0 * a0 * Q0 + 2.f * a0 * b0 * S0) * (1.f / 64.f) + b0 * b0;
            float p1 = (a1 * a1 * Q1 + 2.f * a1 * b1 * S1) * (1.f / 64.f) + b1 * b1;
            float l0 = logf(fmaxf(p0, 1e-6f));
            float l1 = logf(fmaxf(p1, 1e-6f));
            float v0 = l0 * fw_s[lane] + l1 * fw_s[64 + lane];
            float v1 = l0 * fw_s[DHID + lane] + l1 * fw_s[DHID + 64 + lane];
            float v2 = l0 * fw_s[2 * DHID + lane] + l1 * fw_s[2 * DHID + 64 + lane];
#pragma unroll
            for (int off = 32; off; off >>= 1) {
                v0 += __shfl_xor(v0, off);
                v1 += __shfl_xor(v1, off);
                v2 += __shfl_xor(v2, off);
            }
            if (lane == 0) {
                y[(size_t)gg * 3 + 0] = 1.f / (1.f + expf(-(v0 + fb0)));
                y[(size_t)gg * 3 + 1] = 1.f / (1.f + expf(-(v1 + fb1)));
                y[(size_t)gg * 3 + 2] = 1.f / (1.f + expf(-(v2 + fb2)));
            }
        }
    }
}

// ---------------------------------------------------------------------------
extern "C" void kernel_launch(void* const* d_in, const int* in_sizes, int n_in,
                              void* d_out, int out_size, void* d_ws, size_t ws_size,
                              hipStream_t stream) {
    const float* x      = (const float*)d_in[0];
    const int*   ei     = (const int*)d_in[1];
    const float* conv_w = (const float*)d_in[3];
    const float* conv_b = (const float*)d_in[4];
    const float* fc1_w  = (const float*)d_in[5];
    const float* fc1_b  = (const float*)d_in[6];
    const float* rel_w  = (const float*)d_in[7];
    const float* rel_b  = (const float*)d_in[8];
    const float* root_w = (const float*)d_in[9];
    const float* gamma  = (const float*)d_in[10];
    const float* beta   = (const float*)d_in[11];
    const float* fc2_w  = (const float*)d_in[12];
    const float* fc2_b  = (const float*)d_in[13];
    float* y = (float*)d_out;

    int N = in_sizes[2];       // 32768
    int E = in_sizes[1] / 2;   // 1048576
    int G = N / 64;            // 512

    float* Sg     = (float*)d_ws;                  // G*128
    float* Qg     = Sg + (size_t)G * DHID;         // G*128
    float* Wp     = Qg + (size_t)G * DHID;         // 6400 + 64 (b2)
    float* upk    = Wp + 6464;                     // 16384
    unsigned* bar = (unsigned*)(upk + 16384);      // counter

    packU<<<90, 256, 0, stream>>>(conv_w, conv_b, fc1_w, fc1_b, rel_w, root_w,
                                  Wp, upk, bar);
    fused<<<G, 512, 0, stream>>>(x, ei, Wp, upk, rel_b, gamma, beta,
                                 fc2_w, fc2_b, Sg, Qg, y, bar, E, G, N);
}